// Round 22
// baseline (732.482 us; speedup 1.0000x reference)
//
#include <hip/hip_runtime.h>

typedef unsigned short u16;
typedef u16 u16x4 __attribute__((ext_vector_type(4)));
typedef u16 u16x8 __attribute__((ext_vector_type(8)));
typedef __bf16 bf16x8 __attribute__((ext_vector_type(8)));
typedef float f32x4 __attribute__((ext_vector_type(4)));
typedef unsigned u32x4 __attribute__((ext_vector_type(4)));

#define MFMA16 __builtin_amdgcn_mfma_f32_16x16x32_bf16
#define QSCALE 0.17677669529663689f
#define VMWAIT(N) asm volatile("s_waitcnt vmcnt(" #N ")" ::: "memory")

__device__ __forceinline__ u16 f2bf(float f) {
  unsigned u = __builtin_bit_cast(unsigned, f);
  u += 0x7fffu + ((u >> 16) & 1u);
  return (u16)(u >> 16);
}
__device__ __forceinline__ unsigned pk2bf(float a, float b) {
  return (unsigned)f2bf(a) | ((unsigned)f2bf(b) << 16);
}
__device__ __forceinline__ bf16x8 as_bf(u16x8 u) { return __builtin_bit_cast(bf16x8, u); }
__device__ __forceinline__ f32x4 zf4() { f32x4 z = {0.f, 0.f, 0.f, 0.f}; return z; }

// ---------------- prep: weight transpose->bf16, smask3 build ---------------
__global__ __launch_bounds__(256) void prep_kernel(
    const float* __restrict__ wq, const float* __restrict__ wp,
    const float* __restrict__ bt, const int* __restrict__ ri,
    const float* __restrict__ mask,
    u16* __restrict__ wqT, u16* __restrict__ wpT, float* __restrict__ smask3) {
  int idx = blockIdx.x * 256 + threadIdx.x;
  if (idx < 442368) {
    int nn = idx / 384, kk = idx % 384;
    wqT[idx] = f2bf(wq[(size_t)kk * 1152 + nn]);
  } else if (idx < 589824) {
    int i2 = idx - 442368;
    int nn = i2 / 384, kk = i2 % 384;
    wpT[i2] = f2bf(wp[(size_t)kk * 384 + nn]);
  } else if (idx < 786432) {
    int i3 = idx - 589824;
    int g = i3 / 49152;
    int rem = i3 % 49152;
    int h = rem / 4096;
    int nm = rem % 4096;
    int n = nm >> 6;
    int m = nm & 63;
    float v = 0.f;
    if (n < 49 && m < 49)
      v = bt[ri[n * 49 + m] * 12 + h] + mask[g * 2401 + n * 49 + m];
    smask3[i3] = v;
  }
}

// ---------------- conv_x: fp32 x -> bf16 (one pass) ------------------------
__global__ __launch_bounds__(256) void conv_x(const float* __restrict__ x,
                                              u16* __restrict__ xb) {
  size_t i = ((size_t)blockIdx.x * 256 + threadIdx.x) * 8;
  f32x4 a = *(const f32x4*)(x + i);
  f32x4 b = *(const f32x4*)(x + i + 4);
  u16x8 o;
  o[0] = f2bf(a[0]); o[1] = f2bf(a[1]); o[2] = f2bf(a[2]); o[3] = f2bf(a[3]);
  o[4] = f2bf(b[0]); o[5] = f2bf(b[1]); o[6] = f2bf(b[2]); o[7] = f2bf(b[3]);
  *(u16x8*)(xb + i) = o;
}

// ---------------- GEMM v4 (twice-verified): C^T, BK=32, counted vmcnt ------
template <int NCH, bool QKV>
__global__ __launch_bounds__(256) void gemm4(
    const u16* __restrict__ Wt, const u16* __restrict__ Xb,
    const float* __restrict__ bias, void* __restrict__ outp) {
  __shared__ u16 As[2][128 * 32];
  __shared__ u16 Bs[2][128 * 32];
  const int t = threadIdx.x;
  const int l = t & 63, w = t >> 6;

  const int bid = blockIdx.x;
  const int xcd = bid & 7, q = bid >> 3;
  const int logical = xcd * (196 * NCH) + q;
  const int tokt = logical / NCH, cht = logical % NCH;
  const int tb = tokt * 128;
  const int cb = cht * 128;
  const int LDC = NCH * 128;

  f32x4 acc[4][4];
#pragma unroll
  for (int mi = 0; mi < 4; ++mi)
#pragma unroll
    for (int ni = 0; ni < 4; ++ni) acc[mi][ni] = zf4();

  const int rA = (w >> 1) * 64 + (l & 15);
  const int rB = (w & 1) * 64 + (l & 15);
  const int gsel = l >> 4;
  const int gA = ((gsel ^ ((rA >> 1) & 3))) * 8;
  const int gB = ((gsel ^ ((rB >> 1) & 3))) * 8;

  auto stage = [&](int bf, int kt) {
    const int ko = kt * 32;
#pragma unroll
    for (int j = 0; j < 2; ++j) {
      const int gi = j * 256 + t;
      const int row = gi >> 2, slot = gi & 3;
      const int sg = (slot ^ ((row >> 1) & 3)) * 8;
      __builtin_amdgcn_global_load_lds(
          (const __attribute__((address_space(1))) unsigned int*)
              (Wt + (size_t)(cb + row) * 384 + ko + sg),
          (__attribute__((address_space(3))) unsigned int*)(&As[bf][gi * 8]),
          16, 0, 0);
      __builtin_amdgcn_global_load_lds(
          (const __attribute__((address_space(1))) unsigned int*)
              (Xb + (size_t)(tb + row) * 384 + ko + sg),
          (__attribute__((address_space(3))) unsigned int*)(&Bs[bf][gi * 8]),
          16, 0, 0);
    }
  };

  auto kbody = [&](int cur, int ktnext, bool dostage) {
    __builtin_amdgcn_sched_barrier(0);
    __builtin_amdgcn_s_barrier();
    bf16x8 af[4], bfr[4];
#pragma unroll
    for (int mi = 0; mi < 4; ++mi)
      af[mi] = *(const bf16x8*)(&As[cur][(rA + mi * 16) * 32 + gA]);
#pragma unroll
    for (int nj = 0; nj < 4; ++nj)
      bfr[nj] = *(const bf16x8*)(&Bs[cur][(rB + nj * 16) * 32 + gB]);
    asm volatile("s_waitcnt lgkmcnt(0)" ::: "memory");
    __builtin_amdgcn_sched_barrier(0);
    __builtin_amdgcn_s_barrier();
    if (dostage) stage(cur, ktnext);
    __builtin_amdgcn_sched_barrier(0);
    __builtin_amdgcn_s_setprio(1);
#pragma unroll
    for (int mi = 0; mi < 4; ++mi)
#pragma unroll
      for (int nj = 0; nj < 4; ++nj)
        acc[mi][nj] = MFMA16(af[mi], bfr[nj], acc[mi][nj], 0, 0, 0);
    __builtin_amdgcn_s_setprio(0);
  };

  stage(0, 0);
  stage(1, 1);
#pragma unroll
  for (int kt = 0; kt < 10; ++kt) {
    VMWAIT(4);
    kbody(kt & 1, kt + 2, true);
  }
  VMWAIT(4);
  kbody(0, 0, false);
  VMWAIT(0);
  kbody(1, 0, false);

#pragma unroll
  for (int mi = 0; mi < 4; ++mi) {
    const int ch = cb + (w >> 1) * 64 + mi * 16 + (l >> 4) * 4;
    const f32x4 bv = *(const f32x4*)(bias + ch);
#pragma unroll
    for (int nj = 0; nj < 4; ++nj) {
      const int tok = tb + (w & 1) * 64 + nj * 16 + (l & 15);
      if constexpr (QKV) {
        const int qkvi = ch / 384;
        const int rem = ch - qkvi * 384;
        const int hh = rem >> 5;
        const int d = rem & 31;
        const float scl = (qkvi == 0) ? QSCALE : 1.0f;
        u16x4 pk;
#pragma unroll
        for (int r = 0; r < 4; ++r) pk[r] = f2bf((acc[mi][nj][r] + bv[r]) * scl);
        *(u16x4*)((u16*)outp + ((size_t)(qkvi * 12 + hh) * 200704 + tok) * 32 + d) = pk;
      } else {
        f32x4 o;
#pragma unroll
        for (int r = 0; r < 4; ++r) o[r] = acc[mi][nj][r] + bv[r];
        *(f32x4*)((float*)outp + (size_t)tok * LDC + ch) = o;
      }
    }
  }
}

// ---------------- Attention v20: v19 minus s_setprio (scheduler A/B) -------
// Identical to r19/r21-verified in-register-P attention, with all s_setprio
// removed: 16 co-resident waves in different phases should interleave freely
// instead of being starved by whichever wave holds priority 1.
__global__ __launch_bounds__(256, 4) void attn_kernel(
    const u16* __restrict__ qkvb, const float* __restrict__ smask3,
    u16* __restrict__ attnb) {
  __shared__ u16 Vt[4][2336];      // per-head V^T: [d][k] stride 72 + skew
  const int t = threadIdx.x;
  const int l = t & 63, wv = t >> 6;
  const int bid = blockIdx.x;
  const int logical = (bid & 7) * 1536 + (bid >> 3);   // XCD-chunked
  const int b = logical / 3;                            // window
  const int hg = logical % 3;                           // head group
  const int h = hg * 4 + wv;
  u16* Vw = &Vt[wv][0];
  const u16x8 z = {0, 0, 0, 0, 0, 0, 0, 0};

  // V^T staging: coalesced row loads, scatter to [d][k]
#pragma unroll
  for (int i = 0; i < 4; ++i) {
    const int row = i * 16 + (l >> 2);
    const int sg = l & 3;
    u16x8 vv = z;
    if (row < 49)
      vv = *(const u16x8*)(qkvb + ((size_t)(24 + h) * 200704 + b * 49 + row) * 32 + sg * 8);
#pragma unroll
    for (int e = 0; e < 8; ++e) {
      const int d = sg * 8 + e;
      Vw[d * 72 + (d >> 3) * 8 + row] = vv[e];
    }
  }

  // K as A-frags, Q as B-frags (operand-swapped; coalesced)
  const u16* qb = qkvb + ((size_t)h * 200704 + b * 49) * 32 + (l >> 4) * 8;
  const u16* kp = qkvb + ((size_t)(12 + h) * 200704 + b * 49) * 32 + (l >> 4) * 8;
  bf16x8 ka[4], qf[4];
#pragma unroll
  for (int i = 0; i < 4; ++i) {
    const int rr = i * 16 + (l & 15);
    ka[i] = (rr < 49) ? *(const bf16x8*)(kp + rr * 32) : as_bf(z);
    qf[i] = (rr < 49) ? *(const bf16x8*)(qb + rr * 32) : as_bf(z);
  }

  // S^T[m][n]: st[ki][ni][r] with m = ki*16+(l>>4)*4+r, n = ni*16+(l&15)
  f32x4 st[4][4];
#pragma unroll
  for (int ki = 0; ki < 4; ++ki)
#pragma unroll
    for (int ni = 0; ni < 4; ++ni) st[ki][ni] = MFMA16(ka[ki], qf[ni], zf4(), 0, 0, 0);

  // bias + shift mask: one f32x4 per fragment from smask3[n][m0..m0+3]
  const float* sm3 = smask3 + ((size_t)(b & 3) * 12 + h) * 4096;
  const int m0base = (l >> 4) * 4;
#pragma unroll
  for (int ki = 0; ki < 4; ++ki) {
    const int m0 = ki * 16 + m0base;
#pragma unroll
    for (int ni = 0; ni < 4; ++ni) {
      const int n = ni * 16 + (l & 15);
      const f32x4 bv = *(const f32x4*)(sm3 + n * 64 + m0);
#pragma unroll
      for (int r = 0; r < 4; ++r) st[ki][ni][r] += bv[r];
    }
  }
  // mask m >= 49 (ki==3): keep only (l>>4)==0, r==0 (m=48)
  {
    const bool keep48 = ((l >> 4) == 0);
#pragma unroll
    for (int ni = 0; ni < 4; ++ni) {
      st[3][ni][0] = keep48 ? st[3][ni][0] : -1e30f;
      st[3][ni][1] = -1e30f;
      st[3][ni][2] = -1e30f;
      st[3][ni][3] = -1e30f;
    }
  }
  // softmax per ni + pack normalized P to bf16 pairs
  unsigned pkr[4][4][2];
#pragma unroll
  for (int ni = 0; ni < 4; ++ni) {
    float tk[4];
#pragma unroll
    for (int ki = 0; ki < 4; ++ki)
      tk[ki] = fmaxf(fmaxf(st[ki][ni][0], st[ki][ni][1]),
                     fmaxf(st[ki][ni][2], st[ki][ni][3]));
    float mx = fmaxf(fmaxf(tk[0], tk[1]), fmaxf(tk[2], tk[3]));
    mx = fmaxf(mx, __shfl_xor(mx, 16));
    mx = fmaxf(mx, __shfl_xor(mx, 32));
    float es[4];
#pragma unroll
    for (int ki = 0; ki < 4; ++ki) {
      float e0 = 0.f;
#pragma unroll
      for (int r = 0; r < 4; ++r) {
        const float p = __expf(st[ki][ni][r] - mx);
        st[ki][ni][r] = p;
        e0 += p;
      }
      es[ki] = e0;
    }
    float etot = (es[0] + es[1]) + (es[2] + es[3]);
    etot += __shfl_xor(etot, 16);
    etot += __shfl_xor(etot, 32);
    const float inv = 1.0f / etot;
#pragma unroll
    for (int ki = 0; ki < 4; ++ki) {
      pkr[ki][ni][0] = pk2bf(st[ki][ni][0] * inv, st[ki][ni][1] * inv);
      pkr[ki][ni][1] = pk2bf(st[ki][ni][2] * inv, st[ki][ni][3] * inv);
    }
  }

  // drain wave-local V^T scatter before PV reads (wave-local LDS)
  asm volatile("s_waitcnt lgkmcnt(0)" ::: "memory");
  __builtin_amdgcn_sched_barrier(0);

  // O^T[d][n] = sum_k V^T[d][k] P^T[k][n]; pb built via register exchange
  const int c = l & 15;
  const int srcLo = c + ((l >> 4) & 1) * 32;
  const int srcHi = srcLo + 16;
  const bool hiKi = ((l >> 5) & 1) != 0;
  f32x4 ot[2][4];
#pragma unroll
  for (int dj = 0; dj < 2; ++dj)
#pragma unroll
    for (int mi = 0; mi < 4; ++mi) ot[dj][mi] = zf4();
#pragma unroll
  for (int ks = 0; ks < 2; ++ks) {
    bf16x8 va[2];
#pragma unroll
    for (int dj = 0; dj < 2; ++dj) {
      const int d0 = dj * 16 + (l & 15);
      va[dj] = *(const bf16x8*)(Vw + d0 * 72 + (d0 >> 3) * 8 + ks * 32 + (l >> 4) * 8);
    }
#pragma unroll
    for (int mi = 0; mi < 4; ++mi) {
      const int a0 = __shfl((int)pkr[2 * ks][mi][0], srcLo);
      const int a1 = __shfl((int)pkr[2 * ks][mi][1], srcLo);
      const int a2 = __shfl((int)pkr[2 * ks][mi][0], srcHi);
      const int a3 = __shfl((int)pkr[2 * ks][mi][1], srcHi);
      const int b0 = __shfl((int)pkr[2 * ks + 1][mi][0], srcLo);
      const int b1 = __shfl((int)pkr[2 * ks + 1][mi][1], srcLo);
      const int b2 = __shfl((int)pkr[2 * ks + 1][mi][0], srcHi);
      const int b3 = __shfl((int)pkr[2 * ks + 1][mi][1], srcHi);
      u32x4 wv4;
      wv4[0] = (unsigned)(hiKi ? b0 : a0);
      wv4[1] = (unsigned)(hiKi ? b1 : a1);
      wv4[2] = (unsigned)(hiKi ? b2 : a2);
      wv4[3] = (unsigned)(hiKi ? b3 : a3);
      const bf16x8 pb = __builtin_bit_cast(bf16x8, wv4);
#pragma unroll
      for (int dj = 0; dj < 2; ++dj)
        ot[dj][mi] = MFMA16(va[dj], pb, ot[dj][mi], 0, 0, 0);
    }
  }
  // store O^T (attnb stays [tok][384] for proj)
#pragma unroll
  for (int dj = 0; dj < 2; ++dj)
#pragma unroll
    for (int mi = 0; mi < 4; ++mi) {
      const int n = mi * 16 + (l & 15);
      if (n < 49) {
        u16x4 pk;
        pk[0] = f2bf(ot[dj][mi][0]);
        pk[1] = f2bf(ot[dj][mi][1]);
        pk[2] = f2bf(ot[dj][mi][2]);
        pk[3] = f2bf(ot[dj][mi][3]);
        *(u16x4*)(attnb + (size_t)(b * 49 + n) * 384 + h * 32 + dj * 16 + (l >> 4) * 4) = pk;
      }
    }
}

extern "C" void kernel_launch(void* const* d_in, const int* in_sizes, int n_in,
                              void* d_out, int out_size, void* d_ws, size_t ws_size,
                              hipStream_t stream) {
  const float* x       = (const float*)d_in[0];
  const float* mask    = (const float*)d_in[1];
  const float* w_qkv   = (const float*)d_in[2];
  const float* b_qkv   = (const float*)d_in[3];
  const float* bias_t  = (const float*)d_in[4];
  const float* w_proj  = (const float*)d_in[5];
  const float* b_proj  = (const float*)d_in[6];
  const int*   rel_idx = (const int*)d_in[7];
  float* out = (float*)d_out;

  char* ws = (char*)d_ws;
  u16*   wqT    = (u16*)ws;                      // 442368 u16
  u16*   wpT    = (u16*)(ws + 884736);           // 147456 u16
  float* smask3 = (float*)(ws + 1179648);        // 196608 f32 (3145728 B)
  u16*   qkvb   = (u16*)(ws + 4325376);          // 36*200704*32 u16 (dense)
  u16*   xb     = (u16*)(ws + 466747392);        // 200704*384 u16 (aliases attnb)
  u16*   attnb  = (u16*)(ws + 466747392);        // xb dead before attn writes

  prep_kernel<<<3072, 256, 0, stream>>>(w_qkv, w_proj, bias_t, rel_idx, mask,
                                        wqT, wpT, smask3);
  conv_x<<<37632, 256, 0, stream>>>(x, xb);
  gemm4<9, true><<<14112, 256, 0, stream>>>(wqT, xb, b_qkv, qkvb);
  attn_kernel<<<12288, 256, 0, stream>>>(qkvb, smask3, attnb);
  gemm4<3, false><<<4704, 256, 0, stream>>>(wpT, attnb, b_proj, out);
}

// Round 23
// 726.627 us; speedup vs baseline: 1.0081x; 1.0081x over previous
//
#include <hip/hip_runtime.h>

typedef unsigned short u16;
typedef u16 u16x4 __attribute__((ext_vector_type(4)));
typedef u16 u16x8 __attribute__((ext_vector_type(8)));
typedef __bf16 bf16x8 __attribute__((ext_vector_type(8)));
typedef float f32x4 __attribute__((ext_vector_type(4)));
typedef unsigned u32x4 __attribute__((ext_vector_type(4)));

#define MFMA16 __builtin_amdgcn_mfma_f32_16x16x32_bf16
#define QSCALE 0.17677669529663689f
#define VMWAIT(N) asm volatile("s_waitcnt vmcnt(" #N ")" ::: "memory")

__device__ __forceinline__ u16 f2bf(float f) {
  unsigned u = __builtin_bit_cast(unsigned, f);
  u += 0x7fffu + ((u >> 16) & 1u);
  return (u16)(u >> 16);
}
__device__ __forceinline__ unsigned pk2bf(float a, float b) {
  return (unsigned)f2bf(a) | ((unsigned)f2bf(b) << 16);
}
__device__ __forceinline__ bf16x8 as_bf(u16x8 u) { return __builtin_bit_cast(bf16x8, u); }
__device__ __forceinline__ f32x4 zf4() { f32x4 z = {0.f, 0.f, 0.f, 0.f}; return z; }

// ---------------- prep: weight transpose->bf16, smask3 build ---------------
__global__ __launch_bounds__(256) void prep_kernel(
    const float* __restrict__ wq, const float* __restrict__ wp,
    const float* __restrict__ bt, const int* __restrict__ ri,
    const float* __restrict__ mask,
    u16* __restrict__ wqT, u16* __restrict__ wpT, float* __restrict__ smask3) {
  int idx = blockIdx.x * 256 + threadIdx.x;
  if (idx < 442368) {
    int nn = idx / 384, kk = idx % 384;
    wqT[idx] = f2bf(wq[(size_t)kk * 1152 + nn]);
  } else if (idx < 589824) {
    int i2 = idx - 442368;
    int nn = i2 / 384, kk = i2 % 384;
    wpT[i2] = f2bf(wp[(size_t)kk * 384 + nn]);
  } else if (idx < 786432) {
    int i3 = idx - 589824;
    int g = i3 / 49152;
    int rem = i3 % 49152;
    int h = rem / 4096;
    int nm = rem % 4096;
    int n = nm >> 6;
    int m = nm & 63;
    float v = 0.f;
    if (n < 49 && m < 49)
      v = bt[ri[n * 49 + m] * 12 + h] + mask[g * 2401 + n * 49 + m];
    smask3[i3] = v;
  }
}

// ---------------- conv_x: fp32 x -> bf16 (one pass) ------------------------
__global__ __launch_bounds__(256) void conv_x(const float* __restrict__ x,
                                              u16* __restrict__ xb) {
  size_t i = ((size_t)blockIdx.x * 256 + threadIdx.x) * 8;
  f32x4 a = *(const f32x4*)(x + i);
  f32x4 b = *(const f32x4*)(x + i + 4);
  u16x8 o;
  o[0] = f2bf(a[0]); o[1] = f2bf(a[1]); o[2] = f2bf(a[2]); o[3] = f2bf(a[3]);
  o[4] = f2bf(b[0]); o[5] = f2bf(b[1]); o[6] = f2bf(b[2]); o[7] = f2bf(b[3]);
  *(u16x8*)(xb + i) = o;
}

// ---------------- GEMM v4 (twice-verified): C^T, BK=32, counted vmcnt ------
template <int NCH, bool QKV>
__global__ __launch_bounds__(256) void gemm4(
    const u16* __restrict__ Wt, const u16* __restrict__ Xb,
    const float* __restrict__ bias, void* __restrict__ outp) {
  __shared__ u16 As[2][128 * 32];
  __shared__ u16 Bs[2][128 * 32];
  const int t = threadIdx.x;
  const int l = t & 63, w = t >> 6;

  const int bid = blockIdx.x;
  const int xcd = bid & 7, q = bid >> 3;
  const int logical = xcd * (196 * NCH) + q;
  const int tokt = logical / NCH, cht = logical % NCH;
  const int tb = tokt * 128;
  const int cb = cht * 128;
  const int LDC = NCH * 128;

  f32x4 acc[4][4];
#pragma unroll
  for (int mi = 0; mi < 4; ++mi)
#pragma unroll
    for (int ni = 0; ni < 4; ++ni) acc[mi][ni] = zf4();

  const int rA = (w >> 1) * 64 + (l & 15);
  const int rB = (w & 1) * 64 + (l & 15);
  const int gsel = l >> 4;
  const int gA = ((gsel ^ ((rA >> 1) & 3))) * 8;
  const int gB = ((gsel ^ ((rB >> 1) & 3))) * 8;

  auto stage = [&](int bf, int kt) {
    const int ko = kt * 32;
#pragma unroll
    for (int j = 0; j < 2; ++j) {
      const int gi = j * 256 + t;
      const int row = gi >> 2, slot = gi & 3;
      const int sg = (slot ^ ((row >> 1) & 3)) * 8;
      __builtin_amdgcn_global_load_lds(
          (const __attribute__((address_space(1))) unsigned int*)
              (Wt + (size_t)(cb + row) * 384 + ko + sg),
          (__attribute__((address_space(3))) unsigned int*)(&As[bf][gi * 8]),
          16, 0, 0);
      __builtin_amdgcn_global_load_lds(
          (const __attribute__((address_space(1))) unsigned int*)
              (Xb + (size_t)(tb + row) * 384 + ko + sg),
          (__attribute__((address_space(3))) unsigned int*)(&Bs[bf][gi * 8]),
          16, 0, 0);
    }
  };

  auto kbody = [&](int cur, int ktnext, bool dostage) {
    __builtin_amdgcn_sched_barrier(0);
    __builtin_amdgcn_s_barrier();
    bf16x8 af[4], bfr[4];
#pragma unroll
    for (int mi = 0; mi < 4; ++mi)
      af[mi] = *(const bf16x8*)(&As[cur][(rA + mi * 16) * 32 + gA]);
#pragma unroll
    for (int nj = 0; nj < 4; ++nj)
      bfr[nj] = *(const bf16x8*)(&Bs[cur][(rB + nj * 16) * 32 + gB]);
    asm volatile("s_waitcnt lgkmcnt(0)" ::: "memory");
    __builtin_amdgcn_sched_barrier(0);
    __builtin_amdgcn_s_barrier();
    if (dostage) stage(cur, ktnext);
    __builtin_amdgcn_sched_barrier(0);
    __builtin_amdgcn_s_setprio(1);
#pragma unroll
    for (int mi = 0; mi < 4; ++mi)
#pragma unroll
      for (int nj = 0; nj < 4; ++nj)
        acc[mi][nj] = MFMA16(af[mi], bfr[nj], acc[mi][nj], 0, 0, 0);
    __builtin_amdgcn_s_setprio(0);
  };

  stage(0, 0);
  stage(1, 1);
#pragma unroll
  for (int kt = 0; kt < 10; ++kt) {
    VMWAIT(4);
    kbody(kt & 1, kt + 2, true);
  }
  VMWAIT(4);
  kbody(0, 0, false);
  VMWAIT(0);
  kbody(1, 0, false);

#pragma unroll
  for (int mi = 0; mi < 4; ++mi) {
    const int ch = cb + (w >> 1) * 64 + mi * 16 + (l >> 4) * 4;
    const f32x4 bv = *(const f32x4*)(bias + ch);
#pragma unroll
    for (int nj = 0; nj < 4; ++nj) {
      const int tok = tb + (w & 1) * 64 + nj * 16 + (l & 15);
      if constexpr (QKV) {
        const int qkvi = ch / 384;
        const int rem = ch - qkvi * 384;
        const int hh = rem >> 5;
        const int d = rem & 31;
        const float scl = (qkvi == 0) ? QSCALE : 1.0f;
        u16x4 pk;
#pragma unroll
        for (int r = 0; r < 4; ++r) pk[r] = f2bf((acc[mi][nj][r] + bv[r]) * scl);
        *(u16x4*)((u16*)outp + ((size_t)(qkvi * 12 + hh) * 200704 + tok) * 32 + d) = pk;
      } else {
        f32x4 o;
#pragma unroll
        for (int r = 0; r < 4; ++r) o[r] = acc[mi][nj][r] + bv[r];
        *(f32x4*)((float*)outp + (size_t)tok * LDC + ch) = o;
      }
    }
  }
}

// ---------------- Attention v21: v20 with DEFAULT launch bounds ------------
// A/B on the r19-introduced (256,4) bound: if it was clamping VGPR below the
// working set (st+pkr+ka/qf+ot ~ 160+), attn has been spilling to scratch
// since r19.  Let the allocator pick its natural VGPR count.
__global__ __launch_bounds__(256) void attn_kernel(
    const u16* __restrict__ qkvb, const float* __restrict__ smask3,
    u16* __restrict__ attnb) {
  __shared__ u16 Vt[4][2336];      // per-head V^T: [d][k] stride 72 + skew
  const int t = threadIdx.x;
  const int l = t & 63, wv = t >> 6;
  const int bid = blockIdx.x;
  const int logical = (bid & 7) * 1536 + (bid >> 3);   // XCD-chunked
  const int b = logical / 3;                            // window
  const int hg = logical % 3;                           // head group
  const int h = hg * 4 + wv;
  u16* Vw = &Vt[wv][0];
  const u16x8 z = {0, 0, 0, 0, 0, 0, 0, 0};

  // V^T staging: coalesced row loads, scatter to [d][k]
#pragma unroll
  for (int i = 0; i < 4; ++i) {
    const int row = i * 16 + (l >> 2);
    const int sg = l & 3;
    u16x8 vv = z;
    if (row < 49)
      vv = *(const u16x8*)(qkvb + ((size_t)(24 + h) * 200704 + b * 49 + row) * 32 + sg * 8);
#pragma unroll
    for (int e = 0; e < 8; ++e) {
      const int d = sg * 8 + e;
      Vw[d * 72 + (d >> 3) * 8 + row] = vv[e];
    }
  }

  // K as A-frags, Q as B-frags (operand-swapped; coalesced)
  const u16* qb = qkvb + ((size_t)h * 200704 + b * 49) * 32 + (l >> 4) * 8;
  const u16* kp = qkvb + ((size_t)(12 + h) * 200704 + b * 49) * 32 + (l >> 4) * 8;
  bf16x8 ka[4], qf[4];
#pragma unroll
  for (int i = 0; i < 4; ++i) {
    const int rr = i * 16 + (l & 15);
    ka[i] = (rr < 49) ? *(const bf16x8*)(kp + rr * 32) : as_bf(z);
    qf[i] = (rr < 49) ? *(const bf16x8*)(qb + rr * 32) : as_bf(z);
  }

  // S^T[m][n]: st[ki][ni][r] with m = ki*16+(l>>4)*4+r, n = ni*16+(l&15)
  f32x4 st[4][4];
#pragma unroll
  for (int ki = 0; ki < 4; ++ki)
#pragma unroll
    for (int ni = 0; ni < 4; ++ni) st[ki][ni] = MFMA16(ka[ki], qf[ni], zf4(), 0, 0, 0);

  // bias + shift mask: one f32x4 per fragment from smask3[n][m0..m0+3]
  const float* sm3 = smask3 + ((size_t)(b & 3) * 12 + h) * 4096;
  const int m0base = (l >> 4) * 4;
#pragma unroll
  for (int ki = 0; ki < 4; ++ki) {
    const int m0 = ki * 16 + m0base;
#pragma unroll
    for (int ni = 0; ni < 4; ++ni) {
      const int n = ni * 16 + (l & 15);
      const f32x4 bv = *(const f32x4*)(sm3 + n * 64 + m0);
#pragma unroll
      for (int r = 0; r < 4; ++r) st[ki][ni][r] += bv[r];
    }
  }
  // mask m >= 49 (ki==3): keep only (l>>4)==0, r==0 (m=48)
  {
    const bool keep48 = ((l >> 4) == 0);
#pragma unroll
    for (int ni = 0; ni < 4; ++ni) {
      st[3][ni][0] = keep48 ? st[3][ni][0] : -1e30f;
      st[3][ni][1] = -1e30f;
      st[3][ni][2] = -1e30f;
      st[3][ni][3] = -1e30f;
    }
  }
  // softmax per ni + pack normalized P to bf16 pairs
  unsigned pkr[4][4][2];
#pragma unroll
  for (int ni = 0; ni < 4; ++ni) {
    float tk[4];
#pragma unroll
    for (int ki = 0; ki < 4; ++ki)
      tk[ki] = fmaxf(fmaxf(st[ki][ni][0], st[ki][ni][1]),
                     fmaxf(st[ki][ni][2], st[ki][ni][3]));
    float mx = fmaxf(fmaxf(tk[0], tk[1]), fmaxf(tk[2], tk[3]));
    mx = fmaxf(mx, __shfl_xor(mx, 16));
    mx = fmaxf(mx, __shfl_xor(mx, 32));
    float es[4];
#pragma unroll
    for (int ki = 0; ki < 4; ++ki) {
      float e0 = 0.f;
#pragma unroll
      for (int r = 0; r < 4; ++r) {
        const float p = __expf(st[ki][ni][r] - mx);
        st[ki][ni][r] = p;
        e0 += p;
      }
      es[ki] = e0;
    }
    float etot = (es[0] + es[1]) + (es[2] + es[3]);
    etot += __shfl_xor(etot, 16);
    etot += __shfl_xor(etot, 32);
    const float inv = 1.0f / etot;
#pragma unroll
    for (int ki = 0; ki < 4; ++ki) {
      pkr[ki][ni][0] = pk2bf(st[ki][ni][0] * inv, st[ki][ni][1] * inv);
      pkr[ki][ni][1] = pk2bf(st[ki][ni][2] * inv, st[ki][ni][3] * inv);
    }
  }

  // drain wave-local V^T scatter before PV reads (wave-local LDS)
  asm volatile("s_waitcnt lgkmcnt(0)" ::: "memory");
  __builtin_amdgcn_sched_barrier(0);

  // O^T[d][n] = sum_k V^T[d][k] P^T[k][n]; pb built via register exchange
  const int c = l & 15;
  const int srcLo = c + ((l >> 4) & 1) * 32;
  const int srcHi = srcLo + 16;
  const bool hiKi = ((l >> 5) & 1) != 0;
  f32x4 ot[2][4];
#pragma unroll
  for (int dj = 0; dj < 2; ++dj)
#pragma unroll
    for (int mi = 0; mi < 4; ++mi) ot[dj][mi] = zf4();
#pragma unroll
  for (int ks = 0; ks < 2; ++ks) {
    bf16x8 va[2];
#pragma unroll
    for (int dj = 0; dj < 2; ++dj) {
      const int d0 = dj * 16 + (l & 15);
      va[dj] = *(const bf16x8*)(Vw + d0 * 72 + (d0 >> 3) * 8 + ks * 32 + (l >> 4) * 8);
    }
#pragma unroll
    for (int mi = 0; mi < 4; ++mi) {
      const int a0 = __shfl((int)pkr[2 * ks][mi][0], srcLo);
      const int a1 = __shfl((int)pkr[2 * ks][mi][1], srcLo);
      const int a2 = __shfl((int)pkr[2 * ks][mi][0], srcHi);
      const int a3 = __shfl((int)pkr[2 * ks][mi][1], srcHi);
      const int b0 = __shfl((int)pkr[2 * ks + 1][mi][0], srcLo);
      const int b1 = __shfl((int)pkr[2 * ks + 1][mi][1], srcLo);
      const int b2 = __shfl((int)pkr[2 * ks + 1][mi][0], srcHi);
      const int b3 = __shfl((int)pkr[2 * ks + 1][mi][1], srcHi);
      u32x4 wv4;
      wv4[0] = (unsigned)(hiKi ? b0 : a0);
      wv4[1] = (unsigned)(hiKi ? b1 : a1);
      wv4[2] = (unsigned)(hiKi ? b2 : a2);
      wv4[3] = (unsigned)(hiKi ? b3 : a3);
      const bf16x8 pb = __builtin_bit_cast(bf16x8, wv4);
#pragma unroll
      for (int dj = 0; dj < 2; ++dj)
        ot[dj][mi] = MFMA16(va[dj], pb, ot[dj][mi], 0, 0, 0);
    }
  }
  // store O^T (attnb stays [tok][384] for proj)
#pragma unroll
  for (int dj = 0; dj < 2; ++dj)
#pragma unroll
    for (int mi = 0; mi < 4; ++mi) {
      const int n = mi * 16 + (l & 15);
      if (n < 49) {
        u16x4 pk;
        pk[0] = f2bf(ot[dj][mi][0]);
        pk[1] = f2bf(ot[dj][mi][1]);
        pk[2] = f2bf(ot[dj][mi][2]);
        pk[3] = f2bf(ot[dj][mi][3]);
        *(u16x4*)(attnb + (size_t)(b * 49 + n) * 384 + h * 32 + dj * 16 + (l >> 4) * 4) = pk;
      }
    }
}

extern "C" void kernel_launch(void* const* d_in, const int* in_sizes, int n_in,
                              void* d_out, int out_size, void* d_ws, size_t ws_size,
                              hipStream_t stream) {
  const float* x       = (const float*)d_in[0];
  const float* mask    = (const float*)d_in[1];
  const float* w_qkv   = (const float*)d_in[2];
  const float* b_qkv   = (const float*)d_in[3];
  const float* bias_t  = (const float*)d_in[4];
  const float* w_proj  = (const float*)d_in[5];
  const float* b_proj  = (const float*)d_in[6];
  const int*   rel_idx = (const int*)d_in[7];
  float* out = (float*)d_out;

  char* ws = (char*)d_ws;
  u16*   wqT    = (u16*)ws;                      // 442368 u16
  u16*   wpT    = (u16*)(ws + 884736);           // 147456 u16
  float* smask3 = (float*)(ws + 1179648);        // 196608 f32 (3145728 B)
  u16*   qkvb   = (u16*)(ws + 4325376);          // 36*200704*32 u16 (dense)
  u16*   xb     = (u16*)(ws + 466747392);        // 200704*384 u16 (aliases attnb)
  u16*   attnb  = (u16*)(ws + 466747392);        // xb dead before attn writes

  prep_kernel<<<3072, 256, 0, stream>>>(w_qkv, w_proj, bias_t, rel_idx, mask,
                                        wqT, wpT, smask3);
  conv_x<<<37632, 256, 0, stream>>>(x, xb);
  gemm4<9, true><<<14112, 256, 0, stream>>>(wqT, xb, b_qkv, qkvb);
  attn_kernel<<<12288, 256, 0, stream>>>(qkvb, smask3, attnb);
  gemm4<3, false><<<4704, 256, 0, stream>>>(wpT, attnb, b_proj, out);
}

// Round 24
// 687.101 us; speedup vs baseline: 1.0660x; 1.0575x over previous
//
#include <hip/hip_runtime.h>

typedef unsigned short u16;
typedef u16 u16x4 __attribute__((ext_vector_type(4)));
typedef u16 u16x8 __attribute__((ext_vector_type(8)));
typedef __bf16 bf16x8 __attribute__((ext_vector_type(8)));
typedef float f32x4 __attribute__((ext_vector_type(4)));
typedef unsigned u32x4 __attribute__((ext_vector_type(4)));

#define MFMA16 __builtin_amdgcn_mfma_f32_16x16x32_bf16
#define QSCALE 0.17677669529663689f
#define VMWAIT(N) asm volatile("s_waitcnt vmcnt(" #N ")" ::: "memory")

__device__ __forceinline__ u16 f2bf(float f) {
  unsigned u = __builtin_bit_cast(unsigned, f);
  u += 0x7fffu + ((u >> 16) & 1u);
  return (u16)(u >> 16);
}
__device__ __forceinline__ unsigned pk2bf(float a, float b) {
  return (unsigned)f2bf(a) | ((unsigned)f2bf(b) << 16);
}
__device__ __forceinline__ float bf2f(u16 u) {
  return __builtin_bit_cast(float, (unsigned)u << 16);
}
__device__ __forceinline__ bf16x8 as_bf(u16x8 u) { return __builtin_bit_cast(bf16x8, u); }
__device__ __forceinline__ f32x4 zf4() { f32x4 z = {0.f, 0.f, 0.f, 0.f}; return z; }

// ---------------- prep: weight transpose->bf16, smaskP build ---------------
// smaskP layout: [g][h][n(64)][g4(4)][ki(4)][r(4)] bf16, value = bias+mask
// for (n, m = ki*16 + g4*4 + r); 0 outside the 49x49 valid region.
// Lane l (group g4=l>>4) reads its 16 values for row n as ONE contiguous
// 32B run -> 2 u16x8 loads.
__global__ __launch_bounds__(256) void prep_kernel(
    const float* __restrict__ wq, const float* __restrict__ wp,
    const float* __restrict__ bt, const int* __restrict__ ri,
    const float* __restrict__ mask,
    u16* __restrict__ wqT, u16* __restrict__ wpT, u16* __restrict__ smaskP) {
  int idx = blockIdx.x * 256 + threadIdx.x;
  if (idx < 442368) {
    int nn = idx / 384, kk = idx % 384;
    wqT[idx] = f2bf(wq[(size_t)kk * 1152 + nn]);
  } else if (idx < 589824) {
    int i2 = idx - 442368;
    int nn = i2 / 384, kk = i2 % 384;
    wpT[i2] = f2bf(wp[(size_t)kk * 384 + nn]);
  } else if (idx < 786432) {
    int i3 = idx - 589824;
    int g = i3 / 49152;
    int rem = i3 % 49152;
    int h = rem / 4096;
    int nm = rem % 4096;
    int n = nm >> 6;
    int sub = nm & 63;
    int g4 = sub >> 4;
    int ki = (sub >> 2) & 3;
    int r = sub & 3;
    int m = ki * 16 + g4 * 4 + r;
    float v = 0.f;
    if (n < 49 && m < 49)
      v = bt[ri[n * 49 + m] * 12 + h] + mask[g * 2401 + n * 49 + m];
    smaskP[i3] = f2bf(v);
  }
}

// ---------------- conv_x: fp32 x -> bf16 (one pass) ------------------------
__global__ __launch_bounds__(256) void conv_x(const float* __restrict__ x,
                                              u16* __restrict__ xb) {
  size_t i = ((size_t)blockIdx.x * 256 + threadIdx.x) * 8;
  f32x4 a = *(const f32x4*)(x + i);
  f32x4 b = *(const f32x4*)(x + i + 4);
  u16x8 o;
  o[0] = f2bf(a[0]); o[1] = f2bf(a[1]); o[2] = f2bf(a[2]); o[3] = f2bf(a[3]);
  o[4] = f2bf(b[0]); o[5] = f2bf(b[1]); o[6] = f2bf(b[2]); o[7] = f2bf(b[3]);
  *(u16x8*)(xb + i) = o;
}

// ---------------- GEMM v4 (twice-verified): C^T, BK=32, counted vmcnt ------
template <int NCH, bool QKV>
__global__ __launch_bounds__(256) void gemm4(
    const u16* __restrict__ Wt, const u16* __restrict__ Xb,
    const float* __restrict__ bias, void* __restrict__ outp) {
  __shared__ u16 As[2][128 * 32];
  __shared__ u16 Bs[2][128 * 32];
  const int t = threadIdx.x;
  const int l = t & 63, w = t >> 6;

  const int bid = blockIdx.x;
  const int xcd = bid & 7, q = bid >> 3;
  const int logical = xcd * (196 * NCH) + q;
  const int tokt = logical / NCH, cht = logical % NCH;
  const int tb = tokt * 128;
  const int cb = cht * 128;
  const int LDC = NCH * 128;

  f32x4 acc[4][4];
#pragma unroll
  for (int mi = 0; mi < 4; ++mi)
#pragma unroll
    for (int ni = 0; ni < 4; ++ni) acc[mi][ni] = zf4();

  const int rA = (w >> 1) * 64 + (l & 15);
  const int rB = (w & 1) * 64 + (l & 15);
  const int gsel = l >> 4;
  const int gA = ((gsel ^ ((rA >> 1) & 3))) * 8;
  const int gB = ((gsel ^ ((rB >> 1) & 3))) * 8;

  auto stage = [&](int bf, int kt) {
    const int ko = kt * 32;
#pragma unroll
    for (int j = 0; j < 2; ++j) {
      const int gi = j * 256 + t;
      const int row = gi >> 2, slot = gi & 3;
      const int sg = (slot ^ ((row >> 1) & 3)) * 8;
      __builtin_amdgcn_global_load_lds(
          (const __attribute__((address_space(1))) unsigned int*)
              (Wt + (size_t)(cb + row) * 384 + ko + sg),
          (__attribute__((address_space(3))) unsigned int*)(&As[bf][gi * 8]),
          16, 0, 0);
      __builtin_amdgcn_global_load_lds(
          (const __attribute__((address_space(1))) unsigned int*)
              (Xb + (size_t)(tb + row) * 384 + ko + sg),
          (__attribute__((address_space(3))) unsigned int*)(&Bs[bf][gi * 8]),
          16, 0, 0);
    }
  };

  auto kbody = [&](int cur, int ktnext, bool dostage) {
    __builtin_amdgcn_sched_barrier(0);
    __builtin_amdgcn_s_barrier();
    bf16x8 af[4], bfr[4];
#pragma unroll
    for (int mi = 0; mi < 4; ++mi)
      af[mi] = *(const bf16x8*)(&As[cur][(rA + mi * 16) * 32 + gA]);
#pragma unroll
    for (int nj = 0; nj < 4; ++nj)
      bfr[nj] = *(const bf16x8*)(&Bs[cur][(rB + nj * 16) * 32 + gB]);
    asm volatile("s_waitcnt lgkmcnt(0)" ::: "memory");
    __builtin_amdgcn_sched_barrier(0);
    __builtin_amdgcn_s_barrier();
    if (dostage) stage(cur, ktnext);
    __builtin_amdgcn_sched_barrier(0);
    __builtin_amdgcn_s_setprio(1);
#pragma unroll
    for (int mi = 0; mi < 4; ++mi)
#pragma unroll
      for (int nj = 0; nj < 4; ++nj)
        acc[mi][nj] = MFMA16(af[mi], bfr[nj], acc[mi][nj], 0, 0, 0);
    __builtin_amdgcn_s_setprio(0);
  };

  stage(0, 0);
  stage(1, 1);
#pragma unroll
  for (int kt = 0; kt < 10; ++kt) {
    VMWAIT(4);
    kbody(kt & 1, kt + 2, true);
  }
  VMWAIT(4);
  kbody(0, 0, false);
  VMWAIT(0);
  kbody(1, 0, false);

#pragma unroll
  for (int mi = 0; mi < 4; ++mi) {
    const int ch = cb + (w >> 1) * 64 + mi * 16 + (l >> 4) * 4;
    const f32x4 bv = *(const f32x4*)(bias + ch);
#pragma unroll
    for (int nj = 0; nj < 4; ++nj) {
      const int tok = tb + (w & 1) * 64 + nj * 16 + (l & 15);
      if constexpr (QKV) {
        const int qkvi = ch / 384;
        const int rem = ch - qkvi * 384;
        const int hh = rem >> 5;
        const int d = rem & 31;
        const float scl = (qkvi == 0) ? QSCALE : 1.0f;
        u16x4 pk;
#pragma unroll
        for (int r = 0; r < 4; ++r) pk[r] = f2bf((acc[mi][nj][r] + bv[r]) * scl);
        *(u16x4*)((u16*)outp + ((size_t)(qkvi * 12 + hh) * 200704 + tok) * 32 + d) = pk;
      } else {
        f32x4 o;
#pragma unroll
        for (int r = 0; r < 4; ++r) o[r] = acc[mi][nj][r] + bv[r];
        *(f32x4*)((float*)outp + (size_t)tok * LDC + ch) = o;
      }
    }
  }
}

// ---------------- Attention v22: permuted bf16 smask, pre-issued loads -----
// r23-verified structure; smask path changed from 16 dependent f32x4 L2
// loads (on the QK->softmax critical path) to 8 u16x8 loads issued BEFORE
// the QK^T MFMAs (latency hides under matrix work).
__global__ __launch_bounds__(256) void attn_kernel(
    const u16* __restrict__ qkvb, const u16* __restrict__ smaskP,
    u16* __restrict__ attnb) {
  __shared__ u16 Vt[4][2336];      // per-head V^T: [d][k] stride 72 + skew
  const int t = threadIdx.x;
  const int l = t & 63, wv = t >> 6;
  const int bid = blockIdx.x;
  const int logical = (bid & 7) * 1536 + (bid >> 3);   // XCD-chunked
  const int b = logical / 3;                            // window
  const int hg = logical % 3;                           // head group
  const int h = hg * 4 + wv;
  u16* Vw = &Vt[wv][0];
  const u16x8 z = {0, 0, 0, 0, 0, 0, 0, 0};

  // V^T staging: coalesced row loads, scatter to [d][k]
#pragma unroll
  for (int i = 0; i < 4; ++i) {
    const int row = i * 16 + (l >> 2);
    const int sg = l & 3;
    u16x8 vv = z;
    if (row < 49)
      vv = *(const u16x8*)(qkvb + ((size_t)(24 + h) * 200704 + b * 49 + row) * 32 + sg * 8);
#pragma unroll
    for (int e = 0; e < 8; ++e) {
      const int d = sg * 8 + e;
      Vw[d * 72 + (d >> 3) * 8 + row] = vv[e];
    }
  }

  // smask loads issued EARLY (independent of MFMA results)
  const u16* smp = smaskP + ((size_t)(b & 3) * 12 + h) * 4096;
  u16x8 sml[4][2];
#pragma unroll
  for (int ni = 0; ni < 4; ++ni) {
    const int n = ni * 16 + (l & 15);
    const u16* p = smp + n * 64 + (l >> 4) * 16;
    sml[ni][0] = *(const u16x8*)(p);
    sml[ni][1] = *(const u16x8*)(p + 8);
  }

  // K as A-frags, Q as B-frags (operand-swapped; coalesced)
  const u16* qb = qkvb + ((size_t)h * 200704 + b * 49) * 32 + (l >> 4) * 8;
  const u16* kp = qkvb + ((size_t)(12 + h) * 200704 + b * 49) * 32 + (l >> 4) * 8;
  bf16x8 ka[4], qf[4];
#pragma unroll
  for (int i = 0; i < 4; ++i) {
    const int rr = i * 16 + (l & 15);
    ka[i] = (rr < 49) ? *(const bf16x8*)(kp + rr * 32) : as_bf(z);
    qf[i] = (rr < 49) ? *(const bf16x8*)(qb + rr * 32) : as_bf(z);
  }

  // S^T[m][n]: st[ki][ni][r] with m = ki*16+(l>>4)*4+r, n = ni*16+(l&15)
  f32x4 st[4][4];
#pragma unroll
  for (int ki = 0; ki < 4; ++ki)
#pragma unroll
    for (int ni = 0; ni < 4; ++ni) st[ki][ni] = MFMA16(ka[ki], qf[ni], zf4(), 0, 0, 0);

  // bias + shift mask from pre-loaded bf16 registers
#pragma unroll
  for (int ki = 0; ki < 4; ++ki)
#pragma unroll
    for (int ni = 0; ni < 4; ++ni)
#pragma unroll
      for (int r = 0; r < 4; ++r)
        st[ki][ni][r] += bf2f(sml[ni][ki >> 1][(ki & 1) * 4 + r]);

  // mask m >= 49 (ki==3): keep only (l>>4)==0, r==0 (m=48)
  {
    const bool keep48 = ((l >> 4) == 0);
#pragma unroll
    for (int ni = 0; ni < 4; ++ni) {
      st[3][ni][0] = keep48 ? st[3][ni][0] : -1e30f;
      st[3][ni][1] = -1e30f;
      st[3][ni][2] = -1e30f;
      st[3][ni][3] = -1e30f;
    }
  }
  // softmax per ni + pack normalized P to bf16 pairs
  unsigned pkr[4][4][2];
#pragma unroll
  for (int ni = 0; ni < 4; ++ni) {
    float tk[4];
#pragma unroll
    for (int ki = 0; ki < 4; ++ki)
      tk[ki] = fmaxf(fmaxf(st[ki][ni][0], st[ki][ni][1]),
                     fmaxf(st[ki][ni][2], st[ki][ni][3]));
    float mx = fmaxf(fmaxf(tk[0], tk[1]), fmaxf(tk[2], tk[3]));
    mx = fmaxf(mx, __shfl_xor(mx, 16));
    mx = fmaxf(mx, __shfl_xor(mx, 32));
    float es[4];
#pragma unroll
    for (int ki = 0; ki < 4; ++ki) {
      float e0 = 0.f;
#pragma unroll
      for (int r = 0; r < 4; ++r) {
        const float p = __expf(st[ki][ni][r] - mx);
        st[ki][ni][r] = p;
        e0 += p;
      }
      es[ki] = e0;
    }
    float etot = (es[0] + es[1]) + (es[2] + es[3]);
    etot += __shfl_xor(etot, 16);
    etot += __shfl_xor(etot, 32);
    const float inv = 1.0f / etot;
#pragma unroll
    for (int ki = 0; ki < 4; ++ki) {
      pkr[ki][ni][0] = pk2bf(st[ki][ni][0] * inv, st[ki][ni][1] * inv);
      pkr[ki][ni][1] = pk2bf(st[ki][ni][2] * inv, st[ki][ni][3] * inv);
    }
  }

  // drain wave-local V^T scatter before PV reads (wave-local LDS)
  asm volatile("s_waitcnt lgkmcnt(0)" ::: "memory");
  __builtin_amdgcn_sched_barrier(0);

  // O^T[d][n] = sum_k V^T[d][k] P^T[k][n]; pb built via register exchange
  const int c = l & 15;
  const int srcLo = c + ((l >> 4) & 1) * 32;
  const int srcHi = srcLo + 16;
  const bool hiKi = ((l >> 5) & 1) != 0;
  f32x4 ot[2][4];
#pragma unroll
  for (int dj = 0; dj < 2; ++dj)
#pragma unroll
    for (int mi = 0; mi < 4; ++mi) ot[dj][mi] = zf4();
#pragma unroll
  for (int ks = 0; ks < 2; ++ks) {
    bf16x8 va[2];
#pragma unroll
    for (int dj = 0; dj < 2; ++dj) {
      const int d0 = dj * 16 + (l & 15);
      va[dj] = *(const bf16x8*)(Vw + d0 * 72 + (d0 >> 3) * 8 + ks * 32 + (l >> 4) * 8);
    }
#pragma unroll
    for (int mi = 0; mi < 4; ++mi) {
      const int a0 = __shfl((int)pkr[2 * ks][mi][0], srcLo);
      const int a1 = __shfl((int)pkr[2 * ks][mi][1], srcLo);
      const int a2 = __shfl((int)pkr[2 * ks][mi][0], srcHi);
      const int a3 = __shfl((int)pkr[2 * ks][mi][1], srcHi);
      const int b0 = __shfl((int)pkr[2 * ks + 1][mi][0], srcLo);
      const int b1 = __shfl((int)pkr[2 * ks + 1][mi][1], srcLo);
      const int b2 = __shfl((int)pkr[2 * ks + 1][mi][0], srcHi);
      const int b3 = __shfl((int)pkr[2 * ks + 1][mi][1], srcHi);
      u32x4 wv4;
      wv4[0] = (unsigned)(hiKi ? b0 : a0);
      wv4[1] = (unsigned)(hiKi ? b1 : a1);
      wv4[2] = (unsigned)(hiKi ? b2 : a2);
      wv4[3] = (unsigned)(hiKi ? b3 : a3);
      const bf16x8 pb = __builtin_bit_cast(bf16x8, wv4);
#pragma unroll
      for (int dj = 0; dj < 2; ++dj)
        ot[dj][mi] = MFMA16(va[dj], pb, ot[dj][mi], 0, 0, 0);
    }
  }
  // store O^T (attnb stays [tok][384] for proj)
#pragma unroll
  for (int dj = 0; dj < 2; ++dj)
#pragma unroll
    for (int mi = 0; mi < 4; ++mi) {
      const int n = mi * 16 + (l & 15);
      if (n < 49) {
        u16x4 pk;
        pk[0] = f2bf(ot[dj][mi][0]);
        pk[1] = f2bf(ot[dj][mi][1]);
        pk[2] = f2bf(ot[dj][mi][2]);
        pk[3] = f2bf(ot[dj][mi][3]);
        *(u16x4*)(attnb + (size_t)(b * 49 + n) * 384 + h * 32 + dj * 16 + (l >> 4) * 4) = pk;
      }
    }
}

extern "C" void kernel_launch(void* const* d_in, const int* in_sizes, int n_in,
                              void* d_out, int out_size, void* d_ws, size_t ws_size,
                              hipStream_t stream) {
  const float* x       = (const float*)d_in[0];
  const float* mask    = (const float*)d_in[1];
  const float* w_qkv   = (const float*)d_in[2];
  const float* b_qkv   = (const float*)d_in[3];
  const float* bias_t  = (const float*)d_in[4];
  const float* w_proj  = (const float*)d_in[5];
  const float* b_proj  = (const float*)d_in[6];
  const int*   rel_idx = (const int*)d_in[7];
  float* out = (float*)d_out;

  char* ws = (char*)d_ws;
  u16*   wqT    = (u16*)ws;                      // 442368 u16
  u16*   wpT    = (u16*)(ws + 884736);           // 147456 u16
  u16*   smaskP = (u16*)(ws + 1179648);          // 196608 u16 (393216 B)
  u16*   qkvb   = (u16*)(ws + 4325376);          // 36*200704*32 u16 (dense)
  u16*   xb     = (u16*)(ws + 466747392);        // 200704*384 u16 (aliases attnb)
  u16*   attnb  = (u16*)(ws + 466747392);        // xb dead before attn writes

  prep_kernel<<<3072, 256, 0, stream>>>(w_qkv, w_proj, bias_t, rel_idx, mask,
                                        wqT, wpT, smaskP);
  conv_x<<<37632, 256, 0, stream>>>(x, xb);
  gemm4<9, true><<<14112, 256, 0, stream>>>(wqT, xb, b_qkv, qkvb);
  attn_kernel<<<12288, 256, 0, stream>>>(qkvb, smaskP, attnb);
  gemm4<3, false><<<4704, 256, 0, stream>>>(wpT, attnb, b_proj, out);
}

// Round 25
// 678.032 us; speedup vs baseline: 1.0803x; 1.0134x over previous
//
#include <hip/hip_runtime.h>

typedef unsigned short u16;
typedef u16 u16x4 __attribute__((ext_vector_type(4)));
typedef u16 u16x8 __attribute__((ext_vector_type(8)));
typedef __bf16 bf16x8 __attribute__((ext_vector_type(8)));
typedef float f32x4 __attribute__((ext_vector_type(4)));
typedef unsigned u32x4 __attribute__((ext_vector_type(4)));

#define MFMA16 __builtin_amdgcn_mfma_f32_16x16x32_bf16
#define QSCALE 0.17677669529663689f
#define VMWAIT(N) asm volatile("s_waitcnt vmcnt(" #N ")" ::: "memory")

__device__ __forceinline__ u16 f2bf(float f) {
  unsigned u = __builtin_bit_cast(unsigned, f);
  u += 0x7fffu + ((u >> 16) & 1u);
  return (u16)(u >> 16);
}
__device__ __forceinline__ unsigned pk2bf(float a, float b) {
  return (unsigned)f2bf(a) | ((unsigned)f2bf(b) << 16);
}
__device__ __forceinline__ float bf2f(u16 u) {
  return __builtin_bit_cast(float, (unsigned)u << 16);
}
__device__ __forceinline__ bf16x8 as_bf(u16x8 u) { return __builtin_bit_cast(bf16x8, u); }
__device__ __forceinline__ f32x4 zf4() { f32x4 z = {0.f, 0.f, 0.f, 0.f}; return z; }

// ---------------- prep: weight transpose->bf16, smaskP build ---------------
// smaskP layout: [g][h][n(64)][g4(4)][ki(4)][r(4)] bf16  (r24-verified)
__global__ __launch_bounds__(256) void prep_kernel(
    const float* __restrict__ wq, const float* __restrict__ wp,
    const float* __restrict__ bt, const int* __restrict__ ri,
    const float* __restrict__ mask,
    u16* __restrict__ wqT, u16* __restrict__ wpT, u16* __restrict__ smaskP) {
  int idx = blockIdx.x * 256 + threadIdx.x;
  if (idx < 442368) {
    int nn = idx / 384, kk = idx % 384;
    wqT[idx] = f2bf(wq[(size_t)kk * 1152 + nn]);
  } else if (idx < 589824) {
    int i2 = idx - 442368;
    int nn = i2 / 384, kk = i2 % 384;
    wpT[i2] = f2bf(wp[(size_t)kk * 384 + nn]);
  } else if (idx < 786432) {
    int i3 = idx - 589824;
    int g = i3 / 49152;
    int rem = i3 % 49152;
    int h = rem / 4096;
    int nm = rem % 4096;
    int n = nm >> 6;
    int sub = nm & 63;
    int g4 = sub >> 4;
    int ki = (sub >> 2) & 3;
    int r = sub & 3;
    int m = ki * 16 + g4 * 4 + r;
    float v = 0.f;
    if (n < 49 && m < 49)
      v = bt[ri[n * 49 + m] * 12 + h] + mask[g * 2401 + n * 49 + m];
    smaskP[i3] = f2bf(v);
  }
}

// ---------------- conv_x: fp32 x -> bf16 (one pass) ------------------------
__global__ __launch_bounds__(256) void conv_x(const float* __restrict__ x,
                                              u16* __restrict__ xb) {
  size_t i = ((size_t)blockIdx.x * 256 + threadIdx.x) * 8;
  f32x4 a = *(const f32x4*)(x + i);
  f32x4 b = *(const f32x4*)(x + i + 4);
  u16x8 o;
  o[0] = f2bf(a[0]); o[1] = f2bf(a[1]); o[2] = f2bf(a[2]); o[3] = f2bf(a[3]);
  o[4] = f2bf(b[0]); o[5] = f2bf(b[1]); o[6] = f2bf(b[2]); o[7] = f2bf(b[3]);
  *(u16x8*)(xb + i) = o;
}

// ---------------- GEMM v4 (twice-verified): C^T, BK=32, counted vmcnt ------
template <int NCH, bool QKV>
__global__ __launch_bounds__(256) void gemm4(
    const u16* __restrict__ Wt, const u16* __restrict__ Xb,
    const float* __restrict__ bias, void* __restrict__ outp) {
  __shared__ u16 As[2][128 * 32];
  __shared__ u16 Bs[2][128 * 32];
  const int t = threadIdx.x;
  const int l = t & 63, w = t >> 6;

  const int bid = blockIdx.x;
  const int xcd = bid & 7, q = bid >> 3;
  const int logical = xcd * (196 * NCH) + q;
  const int tokt = logical / NCH, cht = logical % NCH;
  const int tb = tokt * 128;
  const int cb = cht * 128;
  const int LDC = NCH * 128;

  f32x4 acc[4][4];
#pragma unroll
  for (int mi = 0; mi < 4; ++mi)
#pragma unroll
    for (int ni = 0; ni < 4; ++ni) acc[mi][ni] = zf4();

  const int rA = (w >> 1) * 64 + (l & 15);
  const int rB = (w & 1) * 64 + (l & 15);
  const int gsel = l >> 4;
  const int gA = ((gsel ^ ((rA >> 1) & 3))) * 8;
  const int gB = ((gsel ^ ((rB >> 1) & 3))) * 8;

  auto stage = [&](int bf, int kt) {
    const int ko = kt * 32;
#pragma unroll
    for (int j = 0; j < 2; ++j) {
      const int gi = j * 256 + t;
      const int row = gi >> 2, slot = gi & 3;
      const int sg = (slot ^ ((row >> 1) & 3)) * 8;
      __builtin_amdgcn_global_load_lds(
          (const __attribute__((address_space(1))) unsigned int*)
              (Wt + (size_t)(cb + row) * 384 + ko + sg),
          (__attribute__((address_space(3))) unsigned int*)(&As[bf][gi * 8]),
          16, 0, 0);
      __builtin_amdgcn_global_load_lds(
          (const __attribute__((address_space(1))) unsigned int*)
              (Xb + (size_t)(tb + row) * 384 + ko + sg),
          (__attribute__((address_space(3))) unsigned int*)(&Bs[bf][gi * 8]),
          16, 0, 0);
    }
  };

  auto kbody = [&](int cur, int ktnext, bool dostage) {
    __builtin_amdgcn_sched_barrier(0);
    __builtin_amdgcn_s_barrier();
    bf16x8 af[4], bfr[4];
#pragma unroll
    for (int mi = 0; mi < 4; ++mi)
      af[mi] = *(const bf16x8*)(&As[cur][(rA + mi * 16) * 32 + gA]);
#pragma unroll
    for (int nj = 0; nj < 4; ++nj)
      bfr[nj] = *(const bf16x8*)(&Bs[cur][(rB + nj * 16) * 32 + gB]);
    asm volatile("s_waitcnt lgkmcnt(0)" ::: "memory");
    __builtin_amdgcn_sched_barrier(0);
    __builtin_amdgcn_s_barrier();
    if (dostage) stage(cur, ktnext);
    __builtin_amdgcn_sched_barrier(0);
    __builtin_amdgcn_s_setprio(1);
#pragma unroll
    for (int mi = 0; mi < 4; ++mi)
#pragma unroll
      for (int nj = 0; nj < 4; ++nj)
        acc[mi][nj] = MFMA16(af[mi], bfr[nj], acc[mi][nj], 0, 0, 0);
    __builtin_amdgcn_s_setprio(0);
  };

  stage(0, 0);
  stage(1, 1);
#pragma unroll
  for (int kt = 0; kt < 10; ++kt) {
    VMWAIT(4);
    kbody(kt & 1, kt + 2, true);
  }
  VMWAIT(4);
  kbody(0, 0, false);
  VMWAIT(0);
  kbody(1, 0, false);

#pragma unroll
  for (int mi = 0; mi < 4; ++mi) {
    const int ch = cb + (w >> 1) * 64 + mi * 16 + (l >> 4) * 4;
    const f32x4 bv = *(const f32x4*)(bias + ch);
#pragma unroll
    for (int nj = 0; nj < 4; ++nj) {
      const int tok = tb + (w & 1) * 64 + nj * 16 + (l & 15);
      if constexpr (QKV) {
        const int qkvi = ch / 384;
        const int rem = ch - qkvi * 384;
        const int hh = rem >> 5;
        const int d = rem & 31;
        const float scl = (qkvi == 0) ? QSCALE : 1.0f;
        u16x4 pk;
#pragma unroll
        for (int r = 0; r < 4; ++r) pk[r] = f2bf((acc[mi][nj][r] + bv[r]) * scl);
        *(u16x4*)((u16*)outp + ((size_t)(qkvi * 12 + hh) * 200704 + tok) * 32 + d) = pk;
      } else {
        f32x4 o;
#pragma unroll
        for (int r = 0; r < 4; ++r) o[r] = acc[mi][nj][r] + bv[r];
        *(f32x4*)((float*)outp + (size_t)tok * LDC + ch) = o;
      }
    }
  }
}

// ---------------- Attention v23: smask folded into MFMA C-operand ----------
// r24-verified structure; two changes: (1) all global loads (smask, Q, K, V)
// issued before any dependent use; (2) QK^T computed as D = K·Q^T + smask
// via the MFMA C input -> the 64-op VALU add pass disappears and sml regs
// die at the MFMA.
__global__ __launch_bounds__(256) void attn_kernel(
    const u16* __restrict__ qkvb, const u16* __restrict__ smaskP,
    u16* __restrict__ attnb) {
  __shared__ u16 Vt[4][2336];      // per-head V^T: [d][k] stride 72 + skew
  const int t = threadIdx.x;
  const int l = t & 63, wv = t >> 6;
  const int bid = blockIdx.x;
  const int logical = (bid & 7) * 1536 + (bid >> 3);   // XCD-chunked
  const int b = logical / 3;                            // window
  const int hg = logical % 3;                           // head group
  const int h = hg * 4 + wv;
  u16* Vw = &Vt[wv][0];
  const u16x8 z = {0, 0, 0, 0, 0, 0, 0, 0};

  // ---- issue ALL global loads first (independent; latency overlaps) ----
  // smask (8 u16x8 equivalents -> 2 per ni)
  const u16* smp = smaskP + ((size_t)(b & 3) * 12 + h) * 4096;
  u16x8 sml[4][2];
#pragma unroll
  for (int ni = 0; ni < 4; ++ni) {
    const int n = ni * 16 + (l & 15);
    const u16* p = smp + n * 64 + (l >> 4) * 16;
    sml[ni][0] = *(const u16x8*)(p);
    sml[ni][1] = *(const u16x8*)(p + 8);
  }
  // Q / K fragments (coalesced, head-dense)
  const u16* qb = qkvb + ((size_t)h * 200704 + b * 49) * 32 + (l >> 4) * 8;
  const u16* kp = qkvb + ((size_t)(12 + h) * 200704 + b * 49) * 32 + (l >> 4) * 8;
  bf16x8 ka[4], qf[4];
#pragma unroll
  for (int i = 0; i < 4; ++i) {
    const int rr = i * 16 + (l & 15);
    ka[i] = (rr < 49) ? *(const bf16x8*)(kp + rr * 32) : as_bf(z);
    qf[i] = (rr < 49) ? *(const bf16x8*)(qb + rr * 32) : as_bf(z);
  }
  // V rows (coalesced)
  u16x8 vrow[4];
#pragma unroll
  for (int i = 0; i < 4; ++i) {
    const int row = i * 16 + (l >> 2);
    vrow[i] = (row < 49)
        ? *(const u16x8*)(qkvb + ((size_t)(24 + h) * 200704 + b * 49 + row) * 32 + (l & 3) * 8)
        : z;
  }

  // V^T scatter to LDS (waits only on V loads; Q/K/smask still in flight)
#pragma unroll
  for (int i = 0; i < 4; ++i) {
    const int row = i * 16 + (l >> 2);
    const int sg = l & 3;
#pragma unroll
    for (int e = 0; e < 8; ++e) {
      const int d = sg * 8 + e;
      Vw[d * 72 + (d >> 3) * 8 + row] = vrow[i][e];
    }
  }

  // S^T = K·Q^T + smask  (smask folded into the MFMA C-operand)
  // st[ki][ni][r]: m = ki*16+(l>>4)*4+r, n = ni*16+(l&15)
  f32x4 st[4][4];
#pragma unroll
  for (int ki = 0; ki < 4; ++ki)
#pragma unroll
    for (int ni = 0; ni < 4; ++ni) {
      f32x4 cin;
#pragma unroll
      for (int r = 0; r < 4; ++r)
        cin[r] = bf2f(sml[ni][ki >> 1][(ki & 1) * 4 + r]);
      st[ki][ni] = MFMA16(ka[ki], qf[ni], cin, 0, 0, 0);
    }

  // mask m >= 49 (ki==3): keep only (l>>4)==0, r==0 (m=48)
  {
    const bool keep48 = ((l >> 4) == 0);
#pragma unroll
    for (int ni = 0; ni < 4; ++ni) {
      st[3][ni][0] = keep48 ? st[3][ni][0] : -1e30f;
      st[3][ni][1] = -1e30f;
      st[3][ni][2] = -1e30f;
      st[3][ni][3] = -1e30f;
    }
  }
  // softmax per ni + pack normalized P to bf16 pairs
  unsigned pkr[4][4][2];
#pragma unroll
  for (int ni = 0; ni < 4; ++ni) {
    float tk[4];
#pragma unroll
    for (int ki = 0; ki < 4; ++ki)
      tk[ki] = fmaxf(fmaxf(st[ki][ni][0], st[ki][ni][1]),
                     fmaxf(st[ki][ni][2], st[ki][ni][3]));
    float mx = fmaxf(fmaxf(tk[0], tk[1]), fmaxf(tk[2], tk[3]));
    mx = fmaxf(mx, __shfl_xor(mx, 16));
    mx = fmaxf(mx, __shfl_xor(mx, 32));
    float es[4];
#pragma unroll
    for (int ki = 0; ki < 4; ++ki) {
      float e0 = 0.f;
#pragma unroll
      for (int r = 0; r < 4; ++r) {
        const float p = __expf(st[ki][ni][r] - mx);
        st[ki][ni][r] = p;
        e0 += p;
      }
      es[ki] = e0;
    }
    float etot = (es[0] + es[1]) + (es[2] + es[3]);
    etot += __shfl_xor(etot, 16);
    etot += __shfl_xor(etot, 32);
    const float inv = 1.0f / etot;
#pragma unroll
    for (int ki = 0; ki < 4; ++ki) {
      pkr[ki][ni][0] = pk2bf(st[ki][ni][0] * inv, st[ki][ni][1] * inv);
      pkr[ki][ni][1] = pk2bf(st[ki][ni][2] * inv, st[ki][ni][3] * inv);
    }
  }

  // drain wave-local V^T scatter before PV reads (wave-local LDS)
  asm volatile("s_waitcnt lgkmcnt(0)" ::: "memory");
  __builtin_amdgcn_sched_barrier(0);

  // O^T[d][n] = sum_k V^T[d][k] P^T[k][n]; pb built via register exchange
  const int c = l & 15;
  const int srcLo = c + ((l >> 4) & 1) * 32;
  const int srcHi = srcLo + 16;
  const bool hiKi = ((l >> 5) & 1) != 0;
  f32x4 ot[2][4];
#pragma unroll
  for (int dj = 0; dj < 2; ++dj)
#pragma unroll
    for (int mi = 0; mi < 4; ++mi) ot[dj][mi] = zf4();
#pragma unroll
  for (int ks = 0; ks < 2; ++ks) {
    bf16x8 va[2];
#pragma unroll
    for (int dj = 0; dj < 2; ++dj) {
      const int d0 = dj * 16 + (l & 15);
      va[dj] = *(const bf16x8*)(Vw + d0 * 72 + (d0 >> 3) * 8 + ks * 32 + (l >> 4) * 8);
    }
#pragma unroll
    for (int mi = 0; mi < 4; ++mi) {
      const int a0 = __shfl((int)pkr[2 * ks][mi][0], srcLo);
      const int a1 = __shfl((int)pkr[2 * ks][mi][1], srcLo);
      const int a2 = __shfl((int)pkr[2 * ks][mi][0], srcHi);
      const int a3 = __shfl((int)pkr[2 * ks][mi][1], srcHi);
      const int b0 = __shfl((int)pkr[2 * ks + 1][mi][0], srcLo);
      const int b1 = __shfl((int)pkr[2 * ks + 1][mi][1], srcLo);
      const int b2 = __shfl((int)pkr[2 * ks + 1][mi][0], srcHi);
      const int b3 = __shfl((int)pkr[2 * ks + 1][mi][1], srcHi);
      u32x4 wv4;
      wv4[0] = (unsigned)(hiKi ? b0 : a0);
      wv4[1] = (unsigned)(hiKi ? b1 : a1);
      wv4[2] = (unsigned)(hiKi ? b2 : a2);
      wv4[3] = (unsigned)(hiKi ? b3 : a3);
      const bf16x8 pb = __builtin_bit_cast(bf16x8, wv4);
#pragma unroll
      for (int dj = 0; dj < 2; ++dj)
        ot[dj][mi] = MFMA16(va[dj], pb, ot[dj][mi], 0, 0, 0);
    }
  }
  // store O^T (attnb stays [tok][384] for proj)
#pragma unroll
  for (int dj = 0; dj < 2; ++dj)
#pragma unroll
    for (int mi = 0; mi < 4; ++mi) {
      const int n = mi * 16 + (l & 15);
      if (n < 49) {
        u16x4 pk;
        pk[0] = f2bf(ot[dj][mi][0]);
        pk[1] = f2bf(ot[dj][mi][1]);
        pk[2] = f2bf(ot[dj][mi][2]);
        pk[3] = f2bf(ot[dj][mi][3]);
        *(u16x4*)(attnb + (size_t)(b * 49 + n) * 384 + h * 32 + dj * 16 + (l >> 4) * 4) = pk;
      }
    }
}

extern "C" void kernel_launch(void* const* d_in, const int* in_sizes, int n_in,
                              void* d_out, int out_size, void* d_ws, size_t ws_size,
                              hipStream_t stream) {
  const float* x       = (const float*)d_in[0];
  const float* mask    = (const float*)d_in[1];
  const float* w_qkv   = (const float*)d_in[2];
  const float* b_qkv   = (const float*)d_in[3];
  const float* bias_t  = (const float*)d_in[4];
  const float* w_proj  = (const float*)d_in[5];
  const float* b_proj  = (const float*)d_in[6];
  const int*   rel_idx = (const int*)d_in[7];
  float* out = (float*)d_out;

  char* ws = (char*)d_ws;
  u16*   wqT    = (u16*)ws;                      // 442368 u16
  u16*   wpT    = (u16*)(ws + 884736);           // 147456 u16
  u16*   smaskP = (u16*)(ws + 1179648);          // 196608 u16 (393216 B)
  u16*   qkvb   = (u16*)(ws + 4325376);          // 36*200704*32 u16 (dense)
  u16*   xb     = (u16*)(ws + 466747392);        // 200704*384 u16 (aliases attnb)
  u16*   attnb  = (u16*)(ws + 466747392);        // xb dead before attn writes

  prep_kernel<<<3072, 256, 0, stream>>>(w_qkv, w_proj, bias_t, rel_idx, mask,
                                        wqT, wpT, smaskP);
  conv_x<<<37632, 256, 0, stream>>>(x, xb);
  gemm4<9, true><<<14112, 256, 0, stream>>>(wqT, xb, b_qkv, qkvb);
  attn_kernel<<<12288, 256, 0, stream>>>(qkvb, smaskP, attnb);
  gemm4<3, false><<<4704, 256, 0, stream>>>(wpT, attnb, b_proj, out);
}